// Round 8
// baseline (779.939 us; speedup 1.0000x reference)
//
#include <hip/hip_runtime.h>
#include <hip/hip_cooperative_groups.h>

namespace cg = cooperative_groups;

#define N_NODES 50000
#define N_EDGES 800000

#define GRID 512
#define BLK 256
#define SMEM_BYTES 33024   // max(P1: 32KB, P5: 64*65*4 + 64*64*4 = 33024)

static __device__ inline unsigned pack_bf16x2(float a, float b) {
    unsigned ua = __float_as_uint(a);
    unsigned ub = __float_as_uint(b);
    unsigned ra = (ua + 0x7fffu + ((ua >> 16) & 1u)) >> 16;        // RNE
    unsigned rb = (ub + 0x7fffu + ((ub >> 16) & 1u)) & 0xffff0000u;
    return ra | rb;
}

__global__ void __launch_bounds__(BLK, 2) mega_kernel(
    const float* __restrict__ h, const float* __restrict__ W1,
    const float* __restrict__ b1, const float* __restrict__ W2,
    const float* __restrict__ b2, const int* __restrict__ src,
    const int* __restrict__ dst, float* __restrict__ out,
    int* __restrict__ deg_in, unsigned* __restrict__ deg_out,
    float* __restrict__ norm_in, int* __restrict__ row_ptr,
    int* __restrict__ bsum, int* __restrict__ eidx, int* __restrict__ rank,
    unsigned short* __restrict__ t1, unsigned short* __restrict__ h1p,
    unsigned short* __restrict__ t2)
{
    extern __shared__ __align__(16) char smem[];
    cg::grid_group grid = cg::this_grid();
    const int t = threadIdx.x;
    const int b = blockIdx.x;
    const int lane = t & 63;
    const int wid = t >> 6;

    // ---------------- P0: zero degree counters ----------------
    {
        int i = b * BLK + t;
        if (i < N_NODES) { deg_in[i] = 0; deg_out[i] = 0u; }
    }
    grid.sync();

    // ---------------- P1: deg_in/rank atomics (role 0) || gemmA t1=bf16(h@W1) (roles 1,2) ----
    {
        const int g = b / 3, r = b - 3 * g;
        if (r == 0) {
            // 171 deg blocks, coalesced 256-chunks, grid-stride
            for (int e = g * BLK + t; e < N_EDGES; e += 171 * BLK)
                rank[e] = atomicAdd(&deg_in[dst[e]], 1);
        } else {
            // 341 gemm blocks over 1563 tiles of 32 rows
            float (*sA)[128] = (float(*)[128])smem;
            float (*sW)[128] = (float(*)[128])(smem + 32 * 128 * 4);
            const int tx = t & 31, ty = t >> 5;
            for (int tile = g * 2 + (r - 1); tile < 1563; tile += 341) {
                const int n0 = tile * 32;
                __syncthreads();   // smem reuse across tiles
                for (int i = t; i < 1024; i += BLK) {
                    int n = i >> 5, c = i & 31;
                    int gn = n0 + n;
                    float4 v = make_float4(0.f, 0.f, 0.f, 0.f);
                    if (gn < N_NODES) v = ((const float4*)(h + (size_t)gn * 128))[c];
                    ((float4*)sA[n])[c] = v;
                }
                float4 acc[4];
                #pragma unroll
                for (int i = 0; i < 4; ++i) acc[i] = make_float4(0.f, 0.f, 0.f, 0.f);
                for (int kc = 0; kc < 4; ++kc) {
                    __syncthreads();
                    for (int i = t; i < 1024; i += BLK) {
                        int k = i >> 5, c = i & 31;
                        ((float4*)sW[k])[c] = ((const float4*)(W1 + (size_t)(kc * 32 + k) * 128))[c];
                    }
                    __syncthreads();
                    #pragma unroll 8
                    for (int k = 0; k < 32; ++k) {
                        float4 w = ((float4*)sW[k])[tx];
                        #pragma unroll
                        for (int ni = 0; ni < 4; ++ni) {
                            float a = sA[ty * 4 + ni][kc * 32 + k];
                            acc[ni].x = fmaf(a, w.x, acc[ni].x);
                            acc[ni].y = fmaf(a, w.y, acc[ni].y);
                            acc[ni].z = fmaf(a, w.z, acc[ni].z);
                            acc[ni].w = fmaf(a, w.w, acc[ni].w);
                        }
                    }
                }
                #pragma unroll
                for (int ni = 0; ni < 4; ++ni) {
                    int gn = n0 + ty * 4 + ni;
                    if (gn < N_NODES) {
                        uint2 p;
                        p.x = pack_bf16x2(acc[ni].x, acc[ni].y);
                        p.y = pack_bf16x2(acc[ni].z, acc[ni].w);
                        ((uint2*)(t1 + (size_t)gn * 128))[tx] = p;
                    }
                }
            }
        }
    }
    grid.sync();

    // ---------------- P2a: per-block (256-node) exclusive scan of deg_in ----------------
    if (b < 196) {
        int* wsum = (int*)smem;
        int i = b * BLK + t;
        int v = (i < N_NODES) ? deg_in[i] : 0;
        int incl = v;
        #pragma unroll
        for (int d = 1; d < 64; d <<= 1) {
            int u = __shfl_up(incl, d, 64);
            if (lane >= d) incl += u;
        }
        if (lane == 63) wsum[wid] = incl;
        __syncthreads();
        int woff = 0, total = 0;
        #pragma unroll
        for (int j = 0; j < 4; ++j) {
            int s = wsum[j];
            if (j < wid) woff += s;
            total += s;
        }
        if (i < N_NODES) row_ptr[i] = woff + incl - v;
        if (t == 0) bsum[b] = total;
    }
    grid.sync();

    // ---------------- P2b: add redundant prefix of block sums; norm_in ----------------
    if (b < 196) {
        int s = 0;
        for (int j = lane; j < b; j += 64) s += bsum[j];
        #pragma unroll
        for (int d = 1; d < 64; d <<= 1) s += __shfl_xor(s, d, 64);
        int i = b * BLK + t;
        if (i < N_NODES) {
            row_ptr[i] += s;
            int dg = deg_in[i]; if (dg == 0) dg = 1;
            norm_in[i] = rsqrtf((float)dg);
        }
        if (b == 0 && t == 0) row_ptr[N_NODES] = N_EDGES;
    }
    grid.sync();

    // ---------------- P3: CSR placement (atomic-free) + deg_out histogram ----------------
    for (int e = b * BLK + t; e < N_EDGES; e += GRID * BLK) {
        int s = src[e];
        eidx[row_ptr[dst[e]] + rank[e]] = s;
        atomicAdd(&deg_out[s], 1u);
    }
    grid.sync();

    // ---------------- P4: pull128 — h1p[n] = bf16(relu(ni*sum no[s]*t1[s] + b1)*no[n]) ----
    for (int node0 = b * 4 + wid; node0 < N_NODES; node0 += GRID * 4) {
        int node = __builtin_amdgcn_readfirstlane(node0);
        const int beg = row_ptr[node];
        const int end = row_ptr[node + 1];
        float2 acc0 = make_float2(0.f, 0.f);
        float2 acc1 = make_float2(0.f, 0.f);
        float2 acc2 = make_float2(0.f, 0.f);
        float2 acc3 = make_float2(0.f, 0.f);
        int j = beg;
        for (; j + 3 < end; j += 4) {
            int s0 = __builtin_amdgcn_readfirstlane(eidx[j]);
            int s1 = __builtin_amdgcn_readfirstlane(eidx[j + 1]);
            int s2 = __builtin_amdgcn_readfirstlane(eidx[j + 2]);
            int s3 = __builtin_amdgcn_readfirstlane(eidx[j + 3]);
            unsigned d0 = deg_out[s0], d1 = deg_out[s1], d2 = deg_out[s2], d3 = deg_out[s3];
            float n0 = rsqrtf((float)(d0 ? d0 : 1u));
            float n1 = rsqrtf((float)(d1 ? d1 : 1u));
            float n2 = rsqrtf((float)(d2 ? d2 : 1u));
            float n3 = rsqrtf((float)(d3 ? d3 : 1u));
            unsigned u0 = ((const unsigned*)(t1 + (size_t)s0 * 128))[lane];
            unsigned u1 = ((const unsigned*)(t1 + (size_t)s1 * 128))[lane];
            unsigned u2 = ((const unsigned*)(t1 + (size_t)s2 * 128))[lane];
            unsigned u3 = ((const unsigned*)(t1 + (size_t)s3 * 128))[lane];
            acc0.x = fmaf(__uint_as_float(u0 << 16), n0, acc0.x);
            acc0.y = fmaf(__uint_as_float(u0 & 0xffff0000u), n0, acc0.y);
            acc1.x = fmaf(__uint_as_float(u1 << 16), n1, acc1.x);
            acc1.y = fmaf(__uint_as_float(u1 & 0xffff0000u), n1, acc1.y);
            acc2.x = fmaf(__uint_as_float(u2 << 16), n2, acc2.x);
            acc2.y = fmaf(__uint_as_float(u2 & 0xffff0000u), n2, acc2.y);
            acc3.x = fmaf(__uint_as_float(u3 << 16), n3, acc3.x);
            acc3.y = fmaf(__uint_as_float(u3 & 0xffff0000u), n3, acc3.y);
        }
        for (; j < end; ++j) {
            int s0 = __builtin_amdgcn_readfirstlane(eidx[j]);
            unsigned d0 = deg_out[s0];
            float n0 = rsqrtf((float)(d0 ? d0 : 1u));
            unsigned u0 = ((const unsigned*)(t1 + (size_t)s0 * 128))[lane];
            acc0.x = fmaf(__uint_as_float(u0 << 16), n0, acc0.x);
            acc0.y = fmaf(__uint_as_float(u0 & 0xffff0000u), n0, acc0.y);
        }
        float ni = norm_in[node];
        unsigned dn = deg_out[node];
        float no = rsqrtf((float)(dn ? dn : 1u));
        float2 bb = ((const float2*)b1)[lane];
        float sx = (acc0.x + acc1.x) + (acc2.x + acc3.x);
        float sy = (acc0.y + acc1.y) + (acc2.y + acc3.y);
        float rx = fmaxf(fmaf(sx, ni, bb.x), 0.f) * no;
        float ry = fmaxf(fmaf(sy, ni, bb.y), 0.f) * no;
        ((unsigned*)(h1p + (size_t)node * 128))[lane] = pack_bf16x2(rx, ry);
    }
    grid.sync();

    // ---------------- P5: gemmB — t2 = bf16(h1p @ W2), 64x64 tile, K chunked by 64 ----------
    {
        float (*sA)[65] = (float(*)[65])smem;                 // [m][k] fp32, +1 pad
        float (*sW)[64] = (float(*)[64])(smem + 64 * 65 * 4); // [k][n] fp32
        const int tm = t & 15;        // rows tm*4..+3
        const int tn = t >> 4;        // cols tn*4..+3
        for (int tile = b; tile < 782; tile += GRID) {
            const int n0 = tile * 64;
            float4 acc[4];
            #pragma unroll
            for (int i = 0; i < 4; ++i) acc[i] = make_float4(0.f, 0.f, 0.f, 0.f);
            for (int kc = 0; kc < 2; ++kc) {
                __syncthreads();
                for (int i = t; i < 1024; i += BLK) {   // A: 64 rows x 16 uint2 (64 feats)
                    int rr = i >> 4, gl = i & 15;
                    int gn = n0 + rr;
                    uint2 u = make_uint2(0u, 0u);
                    if (gn < N_NODES) u = ((const uint2*)(h1p + (size_t)gn * 128))[kc * 16 + gl];
                    int k = gl * 4;
                    sA[rr][k + 0] = __uint_as_float(u.x << 16);
                    sA[rr][k + 1] = __uint_as_float(u.x & 0xffff0000u);
                    sA[rr][k + 2] = __uint_as_float(u.y << 16);
                    sA[rr][k + 3] = __uint_as_float(u.y & 0xffff0000u);
                }
                for (int i = t; i < 1024; i += BLK) {   // W2: 64 k-rows x 16 float4
                    int k = i >> 4, c = i & 15;
                    ((float4*)sW[k])[c] = ((const float4*)(W2 + (size_t)(kc * 64 + k) * 64))[c];
                }
                __syncthreads();
                #pragma unroll 4
                for (int k = 0; k < 64; ++k) {
                    float4 w = ((const float4*)sW[k])[tn];
                    float a0 = sA[tm * 4 + 0][k];
                    float a1 = sA[tm * 4 + 1][k];
                    float a2 = sA[tm * 4 + 2][k];
                    float a3 = sA[tm * 4 + 3][k];
                    acc[0].x = fmaf(a0, w.x, acc[0].x); acc[0].y = fmaf(a0, w.y, acc[0].y);
                    acc[0].z = fmaf(a0, w.z, acc[0].z); acc[0].w = fmaf(a0, w.w, acc[0].w);
                    acc[1].x = fmaf(a1, w.x, acc[1].x); acc[1].y = fmaf(a1, w.y, acc[1].y);
                    acc[1].z = fmaf(a1, w.z, acc[1].z); acc[1].w = fmaf(a1, w.w, acc[1].w);
                    acc[2].x = fmaf(a2, w.x, acc[2].x); acc[2].y = fmaf(a2, w.y, acc[2].y);
                    acc[2].z = fmaf(a2, w.z, acc[2].z); acc[2].w = fmaf(a2, w.w, acc[2].w);
                    acc[3].x = fmaf(a3, w.x, acc[3].x); acc[3].y = fmaf(a3, w.y, acc[3].y);
                    acc[3].z = fmaf(a3, w.z, acc[3].z); acc[3].w = fmaf(a3, w.w, acc[3].w);
                }
            }
            #pragma unroll
            for (int mi = 0; mi < 4; ++mi) {
                int gn = n0 + tm * 4 + mi;
                if (gn < N_NODES) {
                    uint2 p;
                    p.x = pack_bf16x2(acc[mi].x, acc[mi].y);
                    p.y = pack_bf16x2(acc[mi].z, acc[mi].w);
                    ((uint2*)(t2 + (size_t)gn * 64))[tn] = p;
                }
            }
        }
    }
    grid.sync();

    // ---------------- P6: pull64 — out[n] = relu(ni * sum t2[s] + b2) ----------------
    {
        const int half = lane >> 5;
        const int fl = lane & 31;
        for (int node0 = b * 4 + wid; node0 < N_NODES; node0 += GRID * 4) {
            int node = __builtin_amdgcn_readfirstlane(node0);
            const int beg = row_ptr[node];
            const int end = row_ptr[node + 1];
            float2 acc0 = make_float2(0.f, 0.f);
            float2 acc1 = make_float2(0.f, 0.f);
            int j = beg + half;
            for (; j + 2 < end; j += 4) {
                int s0 = eidx[j], s1 = eidx[j + 2];
                unsigned u0 = ((const unsigned*)(t2 + (size_t)s0 * 64))[fl];
                unsigned u1 = ((const unsigned*)(t2 + (size_t)s1 * 64))[fl];
                acc0.x += __uint_as_float(u0 << 16);
                acc0.y += __uint_as_float(u0 & 0xffff0000u);
                acc1.x += __uint_as_float(u1 << 16);
                acc1.y += __uint_as_float(u1 & 0xffff0000u);
            }
            if (j < end) {
                int s0 = eidx[j];
                unsigned u0 = ((const unsigned*)(t2 + (size_t)s0 * 64))[fl];
                acc0.x += __uint_as_float(u0 << 16);
                acc0.y += __uint_as_float(u0 & 0xffff0000u);
            }
            float ax = acc0.x + acc1.x, ay = acc0.y + acc1.y;
            ax += __shfl_xor(ax, 32, 64);
            ay += __shfl_xor(ay, 32, 64);
            if (half == 0) {
                float ni = norm_in[node];
                float2 bb = ((const float2*)b2)[fl];
                float2 r;
                r.x = fmaxf(fmaf(ax, ni, bb.x), 0.f);
                r.y = fmaxf(fmaf(ay, ni, bb.y), 0.f);
                ((float2*)(out + (size_t)node * 64))[fl] = r;
            }
        }
    }
}

extern "C" void kernel_launch(void* const* d_in, const int* in_sizes, int n_in,
                              void* d_out, int out_size, void* d_ws, size_t ws_size,
                              hipStream_t stream) {
    const float* h  = (const float*)d_in[0];
    const float* W1 = (const float*)d_in[1];
    const float* b1 = (const float*)d_in[2];
    const float* W2 = (const float*)d_in[3];
    const float* b2 = (const float*)d_in[4];
    const int* src  = (const int*)d_in[5];
    const int* dst  = (const int*)d_in[6];
    float* out = (float*)d_out;

    char* ws = (char*)d_ws;
    size_t off = 0;
    auto alloc = [&](size_t bytes) {
        void* p = ws + off;
        off = (off + bytes + 255) & ~(size_t)255;
        return p;
    };
    int* deg_in        = (int*)alloc(N_NODES * sizeof(int));
    unsigned* deg_out  = (unsigned*)alloc(N_NODES * sizeof(unsigned));
    float* norm_in     = (float*)alloc(N_NODES * sizeof(float));
    int* row_ptr       = (int*)alloc((N_NODES + 1) * sizeof(int));
    int* bsum          = (int*)alloc(256 * sizeof(int));
    int* eidx          = (int*)alloc((size_t)N_EDGES * sizeof(int));                      // 3.2 MB
    int* rank          = (int*)alloc((size_t)N_EDGES * sizeof(int));                      // 3.2 MB
    unsigned short* t1  = (unsigned short*)alloc((size_t)N_NODES * 128 * sizeof(short));  // 12.8 MB bf16
    unsigned short* h1p = (unsigned short*)alloc((size_t)N_NODES * 128 * sizeof(short));  // 12.8 MB bf16
    unsigned short* t2  = (unsigned short*)alloc((size_t)N_NODES * 64 * sizeof(short));   // 6.4 MB bf16

    void* kargs[] = {
        (void*)&h, (void*)&W1, (void*)&b1, (void*)&W2, (void*)&b2,
        (void*)&src, (void*)&dst, (void*)&out,
        (void*)&deg_in, (void*)&deg_out, (void*)&norm_in, (void*)&row_ptr,
        (void*)&bsum, (void*)&eidx, (void*)&rank,
        (void*)&t1, (void*)&h1p, (void*)&t2
    };
    hipLaunchCooperativeKernel((void*)mega_kernel, dim3(GRID), dim3(BLK),
                               kargs, SMEM_BYTES, stream);
}

// Round 9
// 274.736 us; speedup vs baseline: 2.8389x; 2.8389x over previous
//
#include <hip/hip_runtime.h>

#define N_NODES 50000
#define N_EDGES 800000

#define DEG_CHUNKS 782      // 782*1024 >= 800000 edges, 4 edges/thread
#define GEMMA_TILES 1563    // ceil(50000/32)
#define FUSED1_GRID (3 * DEG_CHUNKS)   // role = blockIdx%3: 0 -> atomics, 1/2 -> gemm
#define SCAN_BLK 1024
#define SCAN_GRID 49        // 49*1024 = 50176 >= 50000

static __device__ inline unsigned pack_bf16x2(float a, float b) {
    unsigned ua = __float_as_uint(a);
    unsigned ub = __float_as_uint(b);
    unsigned ra = (ua + 0x7fffu + ((ua >> 16) & 1u)) >> 16;        // RNE
    unsigned rb = (ub + 0x7fffu + ((ub >> 16) & 1u)) & 0xffff0000u;
    return ra | rb;
}

// ---- zero both degree arrays in one dispatch ----
__global__ __launch_bounds__(256) void zero_kernel(int* __restrict__ deg_in,
                                                   unsigned* __restrict__ deg_out) {
    int i = blockIdx.x * 256 + threadIdx.x;
    if (i < N_NODES) { deg_in[i] = 0; deg_out[i] = 0u; }
}

// ---- fused launch: deg atomics (role 0) interleaved with gemmA (roles 1,2) ----
// deg role:  rank[e] = deg_in[dst]++;  deg_out[src]++   (1.6M scattered atomics)
// gemm role: t1 = bf16(h @ W1)                          (VALU work hides the atomics)
__global__ __launch_bounds__(256) void fused1_kernel(const int* __restrict__ src,
                                                     const int* __restrict__ dst,
                                                     int* __restrict__ deg_in,
                                                     unsigned* __restrict__ deg_out,
                                                     int* __restrict__ rank,
                                                     const float* __restrict__ h,
                                                     const float* __restrict__ W1,
                                                     unsigned short* __restrict__ t1) {
    __shared__ float sA[32][128];
    __shared__ float sW[32][128];

    const int g = blockIdx.x / 3;
    const int r = blockIdx.x - 3 * g;

    if (r == 0) {
        const int base = g * 1024 + threadIdx.x;
        #pragma unroll
        for (int i = 0; i < 4; ++i) {
            int e = base + i * 256;
            if (e < N_EDGES) {
                int s = src[e];
                int d = dst[e];
                rank[e] = atomicAdd(&deg_in[d], 1);
                atomicAdd(&deg_out[s], 1u);
            }
        }
        return;
    }

    const int tile = g * 2 + (r - 1);
    if (tile >= GEMMA_TILES) return;

    const int t  = threadIdx.x;
    const int tx = t & 31;
    const int ty = t >> 5;
    const int n0 = tile * 32;

    for (int i = t; i < 1024; i += 256) {
        int n = i >> 5, c = i & 31;
        int gn = n0 + n;
        float4 v = make_float4(0.f, 0.f, 0.f, 0.f);
        if (gn < N_NODES) v = ((const float4*)(h + (size_t)gn * 128))[c];
        ((float4*)sA[n])[c] = v;
    }

    float4 acc[4];
    #pragma unroll
    for (int i = 0; i < 4; ++i) acc[i] = make_float4(0.f, 0.f, 0.f, 0.f);

    for (int kc = 0; kc < 4; ++kc) {
        __syncthreads();
        for (int i = t; i < 1024; i += 256) {
            int k = i >> 5, c = i & 31;
            ((float4*)sW[k])[c] = ((const float4*)(W1 + (size_t)(kc * 32 + k) * 128))[c];
        }
        __syncthreads();
        #pragma unroll 8
        for (int k = 0; k < 32; ++k) {
            float4 w = ((float4*)sW[k])[tx];
            #pragma unroll
            for (int ni = 0; ni < 4; ++ni) {
                float a = sA[ty * 4 + ni][kc * 32 + k];
                acc[ni].x = fmaf(a, w.x, acc[ni].x);
                acc[ni].y = fmaf(a, w.y, acc[ni].y);
                acc[ni].z = fmaf(a, w.z, acc[ni].z);
                acc[ni].w = fmaf(a, w.w, acc[ni].w);
            }
        }
    }

    #pragma unroll
    for (int ni = 0; ni < 4; ++ni) {
        int gn = n0 + ty * 4 + ni;
        if (gn < N_NODES) {
            uint2 p;
            p.x = pack_bf16x2(acc[ni].x, acc[ni].y);
            p.y = pack_bf16x2(acc[ni].z, acc[ni].w);
            ((uint2*)(t1 + (size_t)gn * 128))[tx] = p;
        }
    }
}

// ---- scan phase 1 ----
__global__ __launch_bounds__(SCAN_BLK) void scan1_kernel(const int* __restrict__ deg_in,
                                                         int* __restrict__ row_ptr,
                                                         int* __restrict__ bsum) {
    __shared__ int wsum[16];
    const int t = threadIdx.x, lane = t & 63, w = t >> 6;
    const int i = blockIdx.x * SCAN_BLK + t;
    int v = (i < N_NODES) ? deg_in[i] : 0;
    int incl = v;
    #pragma unroll
    for (int d = 1; d < 64; d <<= 1) {
        int u = __shfl_up(incl, d, 64);
        if (lane >= d) incl += u;
    }
    if (lane == 63) wsum[w] = incl;
    __syncthreads();
    int woff = 0, total = 0;
    #pragma unroll
    for (int j = 0; j < 16; ++j) {
        int s = wsum[j];
        if (j < w) woff += s;
        total += s;
    }
    if (i < N_NODES) row_ptr[i] = woff + incl - v;
    if (t == 0) bsum[blockIdx.x] = total;
}

// ---- scan phase 2 ----
__global__ __launch_bounds__(64) void scan2_kernel(int* __restrict__ bsum) {
    const int t = threadIdx.x;
    int v = (t < SCAN_GRID) ? bsum[t] : 0;
    int incl = v;
    #pragma unroll
    for (int d = 1; d < 64; d <<= 1) {
        int u = __shfl_up(incl, d, 64);
        if (t >= d) incl += u;
    }
    if (t < SCAN_GRID) bsum[t] = incl - v;
}

// ---- scan phase 3 + both norms (deg_out complete after fused1) ----
__global__ __launch_bounds__(SCAN_BLK) void scan3_norm_kernel(int* __restrict__ row_ptr,
                                                              const int* __restrict__ bsum,
                                                              const int* __restrict__ deg_in,
                                                              const unsigned* __restrict__ deg_out,
                                                              float* __restrict__ norm_out,
                                                              float* __restrict__ norm_in) {
    const int i = blockIdx.x * SCAN_BLK + threadIdx.x;
    if (i < N_NODES) {
        row_ptr[i] += bsum[blockIdx.x];
        unsigned a = deg_out[i]; if (a == 0u) a = 1u;
        int b = deg_in[i];       if (b == 0)  b = 1;
        norm_out[i] = rsqrtf((float)a);
        norm_in[i]  = rsqrtf((float)b);
    }
    if (i == 0) row_ptr[N_NODES] = N_EDGES;
}

// ---- atomic-free CSR placement ----
__global__ __launch_bounds__(256) void place_kernel(const int* __restrict__ src,
                                                    const int* __restrict__ dst,
                                                    const int* __restrict__ row_ptr,
                                                    const int* __restrict__ rank,
                                                    int* __restrict__ eidx) {
    int e = blockIdx.x * 256 + threadIdx.x;
    if (e < N_EDGES) eidx[row_ptr[dst[e]] + rank[e]] = src[e];
}

// ---------------- pull128: half-wave per edge, uint2 (4 bf16) per lane ----------------
// h1p[n] = bf16( relu(norm_in[n] * sum_{s->n} norm_out[s]*t1[s] + b1) * norm_out[n] )
__global__ __launch_bounds__(256) void pull128_kernel(const unsigned short* __restrict__ xb,
                                                      const int* __restrict__ row_ptr,
                                                      const int* __restrict__ eidx,
                                                      const float* __restrict__ b1,
                                                      const float* __restrict__ norm_in,
                                                      const float* __restrict__ norm_out,
                                                      unsigned short* __restrict__ outb) {
    const int node = blockIdx.x * 4 + (threadIdx.x >> 6);
    const int lane = threadIdx.x & 63;
    const int half = lane >> 5;    // 0: even edges, 1: odd edges
    const int fl = lane & 31;      // uint2 group: feats 4fl..4fl+3
    const int beg = row_ptr[node];
    const int end = row_ptr[node + 1];

    float4 acc0 = make_float4(0.f, 0.f, 0.f, 0.f);
    float4 acc1 = make_float4(0.f, 0.f, 0.f, 0.f);
    int j = beg + half;
    for (; j + 2 < end; j += 4) {
        int s0 = eidx[j], s1 = eidx[j + 2];
        float n0 = norm_out[s0], n1 = norm_out[s1];
        uint2 u0 = ((const uint2*)(xb + (size_t)s0 * 128))[fl];
        uint2 u1 = ((const uint2*)(xb + (size_t)s1 * 128))[fl];
        acc0.x = fmaf(__uint_as_float(u0.x << 16), n0, acc0.x);
        acc0.y = fmaf(__uint_as_float(u0.x & 0xffff0000u), n0, acc0.y);
        acc0.z = fmaf(__uint_as_float(u0.y << 16), n0, acc0.z);
        acc0.w = fmaf(__uint_as_float(u0.y & 0xffff0000u), n0, acc0.w);
        acc1.x = fmaf(__uint_as_float(u1.x << 16), n1, acc1.x);
        acc1.y = fmaf(__uint_as_float(u1.x & 0xffff0000u), n1, acc1.y);
        acc1.z = fmaf(__uint_as_float(u1.y << 16), n1, acc1.z);
        acc1.w = fmaf(__uint_as_float(u1.y & 0xffff0000u), n1, acc1.w);
    }
    if (j < end) {
        int s0 = eidx[j];
        float n0 = norm_out[s0];
        uint2 u0 = ((const uint2*)(xb + (size_t)s0 * 128))[fl];
        acc0.x = fmaf(__uint_as_float(u0.x << 16), n0, acc0.x);
        acc0.y = fmaf(__uint_as_float(u0.x & 0xffff0000u), n0, acc0.y);
        acc0.z = fmaf(__uint_as_float(u0.y << 16), n0, acc0.z);
        acc0.w = fmaf(__uint_as_float(u0.y & 0xffff0000u), n0, acc0.w);
    }
    float sx = acc0.x + acc1.x;
    float sy = acc0.y + acc1.y;
    float sz = acc0.z + acc1.z;
    float sw = acc0.w + acc1.w;
    sx += __shfl_xor(sx, 32, 64);
    sy += __shfl_xor(sy, 32, 64);
    sz += __shfl_xor(sz, 32, 64);
    sw += __shfl_xor(sw, 32, 64);
    if (half == 0) {
        float ni = norm_in[node];
        float no = norm_out[node];
        float4 bb = ((const float4*)b1)[fl];
        uint2 p;
        p.x = pack_bf16x2(fmaxf(fmaf(sx, ni, bb.x), 0.f) * no,
                          fmaxf(fmaf(sy, ni, bb.y), 0.f) * no);
        p.y = pack_bf16x2(fmaxf(fmaf(sz, ni, bb.z), 0.f) * no,
                          fmaxf(fmaf(sw, ni, bb.w), 0.f) * no);
        ((uint2*)(outb + (size_t)node * 128))[fl] = p;
    }
}

// ---------------- GEMM-B: t2 = bf16( h1p(bf16) @ W2 )  64x64 tile, 4x4 reg blocking ----------------
__global__ __launch_bounds__(256) void gemmB_kernel(const unsigned short* __restrict__ h1pb,
                                                    const float* __restrict__ W2,
                                                    unsigned short* __restrict__ t2b) {
    __shared__ float sAT[128][64];   // 32 KB, [k][m]
    __shared__ float sW[128][64];    // 32 KB, [k][n]
    const int t  = threadIdx.x;
    const int n0 = blockIdx.x * 64;

    // stage A transposed: 64 rows x 32 uint2-groups (4 bf16 feats each) -> covers k=0..127
    for (int i = t; i < 2048; i += 256) {
        int rr = i >> 5, g = i & 31;
        int gn = n0 + rr;
        uint2 u = make_uint2(0u, 0u);
        if (gn < N_NODES) u = ((const uint2*)(h1pb + (size_t)gn * 128))[g];
        int k = g * 4;
        sAT[k + 0][rr] = __uint_as_float(u.x << 16);
        sAT[k + 1][rr] = __uint_as_float(u.x & 0xffff0000u);
        sAT[k + 2][rr] = __uint_as_float(u.y << 16);
        sAT[k + 3][rr] = __uint_as_float(u.y & 0xffff0000u);
    }
    // stage W2 (fp32): 128 rows x 16 float4-groups
    for (int i = t; i < 2048; i += 256) {
        int k = i >> 4, c = i & 15;
        ((float4*)sW[k])[c] = ((const float4*)(W2 + (size_t)k * 64))[c];
    }
    __syncthreads();

    const int tm = t & 15;    // 4 rows: tm*4..+3
    const int tn = t >> 4;    // 4 cols: tn*4..+3
    float4 acc[4];
    #pragma unroll
    for (int i = 0; i < 4; ++i) acc[i] = make_float4(0.f, 0.f, 0.f, 0.f);

    #pragma unroll 4
    for (int k = 0; k < 128; ++k) {
        float4 a = ((const float4*)sAT[k])[tm];
        float4 w = ((const float4*)sW[k])[tn];
        acc[0].x = fmaf(a.x, w.x, acc[0].x); acc[0].y = fmaf(a.x, w.y, acc[0].y);
        acc[0].z = fmaf(a.x, w.z, acc[0].z); acc[0].w = fmaf(a.x, w.w, acc[0].w);
        acc[1].x = fmaf(a.y, w.x, acc[1].x); acc[1].y = fmaf(a.y, w.y, acc[1].y);
        acc[1].z = fmaf(a.y, w.z, acc[1].z); acc[1].w = fmaf(a.y, w.w, acc[1].w);
        acc[2].x = fmaf(a.z, w.x, acc[2].x); acc[2].y = fmaf(a.z, w.y, acc[2].y);
        acc[2].z = fmaf(a.z, w.z, acc[2].z); acc[2].w = fmaf(a.z, w.w, acc[2].w);
        acc[3].x = fmaf(a.w, w.x, acc[3].x); acc[3].y = fmaf(a.w, w.y, acc[3].y);
        acc[3].z = fmaf(a.w, w.z, acc[3].z); acc[3].w = fmaf(a.w, w.w, acc[3].w);
    }

    #pragma unroll
    for (int mi = 0; mi < 4; ++mi) {
        int gn = n0 + tm * 4 + mi;
        if (gn < N_NODES) {
            uint2 p;
            p.x = pack_bf16x2(acc[mi].x, acc[mi].y);
            p.y = pack_bf16x2(acc[mi].z, acc[mi].w);
            ((uint2*)(t2b + (size_t)gn * 64))[tn] = p;
        }
    }
}

// ---------------- pull64: half-wave per edge, u32 (2 bf16) per lane ----------------
// out[n] = relu(norm_in[n] * sum_{s->n} t2[s] + b2)
__global__ __launch_bounds__(256) void pull64_kernel(const unsigned short* __restrict__ xb,
                                                     const int* __restrict__ row_ptr,
                                                     const int* __restrict__ eidx,
                                                     const float* __restrict__ b2,
                                                     const float* __restrict__ norm_in,
                                                     float* __restrict__ out) {
    const int node = blockIdx.x * 4 + (threadIdx.x >> 6);
    const int lane = threadIdx.x & 63;
    const int half = lane >> 5;
    const int fl = lane & 31;     // u32 group: feats 2fl, 2fl+1
    const int beg = row_ptr[node];
    const int end = row_ptr[node + 1];

    float2 acc0 = make_float2(0.f, 0.f);
    float2 acc1 = make_float2(0.f, 0.f);
    int j = beg + half;
    for (; j + 2 < end; j += 4) {
        int s0 = eidx[j], s1 = eidx[j + 2];
        unsigned u0 = ((const unsigned*)(xb + (size_t)s0 * 64))[fl];
        unsigned u1 = ((const unsigned*)(xb + (size_t)s1 * 64))[fl];
        acc0.x += __uint_as_float(u0 << 16);
        acc0.y += __uint_as_float(u0 & 0xffff0000u);
        acc1.x += __uint_as_float(u1 << 16);
        acc1.y += __uint_as_float(u1 & 0xffff0000u);
    }
    if (j < end) {
        int s0 = eidx[j];
        unsigned u0 = ((const unsigned*)(xb + (size_t)s0 * 64))[fl];
        acc0.x += __uint_as_float(u0 << 16);
        acc0.y += __uint_as_float(u0 & 0xffff0000u);
    }
    float ax = acc0.x + acc1.x, ay = acc0.y + acc1.y;
    ax += __shfl_xor(ax, 32, 64);
    ay += __shfl_xor(ay, 32, 64);
    if (half == 0) {
        float ni = norm_in[node];
        float2 bb = ((const float2*)b2)[fl];
        float2 r;
        r.x = fmaxf(fmaf(ax, ni, bb.x), 0.f);
        r.y = fmaxf(fmaf(ay, ni, bb.y), 0.f);
        ((float2*)(out + (size_t)node * 64))[fl] = r;
    }
}

extern "C" void kernel_launch(void* const* d_in, const int* in_sizes, int n_in,
                              void* d_out, int out_size, void* d_ws, size_t ws_size,
                              hipStream_t stream) {
    const float* h  = (const float*)d_in[0];
    const float* W1 = (const float*)d_in[1];
    const float* b1 = (const float*)d_in[2];
    const float* W2 = (const float*)d_in[3];
    const float* b2 = (const float*)d_in[4];
    const int* src  = (const int*)d_in[5];
    const int* dst  = (const int*)d_in[6];
    float* out = (float*)d_out;

    char* ws = (char*)d_ws;
    size_t off = 0;
    auto alloc = [&](size_t bytes) {
        void* p = ws + off;
        off = (off + bytes + 255) & ~(size_t)255;
        return p;
    };
    int* deg_in        = (int*)alloc(N_NODES * sizeof(int));
    unsigned* deg_out  = (unsigned*)alloc(N_NODES * sizeof(unsigned));
    float* norm_out    = (float*)alloc(N_NODES * sizeof(float));
    float* norm_in     = (float*)alloc(N_NODES * sizeof(float));
    int* row_ptr       = (int*)alloc((N_NODES + 1) * sizeof(int));
    int* bsum          = (int*)alloc(SCAN_GRID * sizeof(int));
    int* eidx          = (int*)alloc((size_t)N_EDGES * sizeof(int));                      // 3.2 MB
    int* rank          = (int*)alloc((size_t)N_EDGES * sizeof(int));                      // 3.2 MB
    unsigned short* t1  = (unsigned short*)alloc((size_t)N_NODES * 128 * sizeof(short));  // 12.8 MB bf16
    unsigned short* h1p = (unsigned short*)alloc((size_t)N_NODES * 128 * sizeof(short));  // 12.8 MB bf16
    unsigned short* t2  = (unsigned short*)alloc((size_t)N_NODES * 64 * sizeof(short));   // 6.4 MB bf16

    // zero degree counters (one dispatch)
    zero_kernel<<<(N_NODES + 255) / 256, 256, 0, stream>>>(deg_in, deg_out);

    // fused: both atomic streams co-resident with gemmA (t1 = bf16(h @ W1))
    fused1_kernel<<<FUSED1_GRID, 256, 0, stream>>>(src, dst, deg_in, deg_out, rank, h, W1, t1);

    // parallel scan -> row_ptr, plus norms
    scan1_kernel<<<SCAN_GRID, SCAN_BLK, 0, stream>>>(deg_in, row_ptr, bsum);
    scan2_kernel<<<1, 64, 0, stream>>>(bsum);
    scan3_norm_kernel<<<SCAN_GRID, SCAN_BLK, 0, stream>>>(row_ptr, bsum, deg_in, deg_out,
                                                          norm_out, norm_in);

    // atomic-free CSR placement
    place_kernel<<<(N_EDGES + 255) / 256, 256, 0, stream>>>(src, dst, row_ptr, rank, eidx);

    // layer 1 pull (half-wave uint2 bf16 gather)
    pull128_kernel<<<N_NODES / 4, 256, 0, stream>>>(t1, row_ptr, eidx, b1, norm_in, norm_out, h1p);

    // layer 2
    gemmB_kernel<<<(N_NODES + 63) / 64, 256, 0, stream>>>(h1p, W2, t2);
    pull64_kernel<<<N_NODES / 4, 256, 0, stream>>>(t2, row_ptr, eidx, b2, norm_in, out);
}